// Round 9
// baseline (747.457 us; speedup 1.0000x reference)
//
#include <hip/hip_runtime.h>

typedef unsigned long long ull;

#define NUM_K   512
#define DIM     64
#define N_ROWS  (32 * 64 * 64)     // 131072 rows
#define HW      4096               // 64*64
#define CHW     (64 * 4096)        // per-batch stride (C*H*W)

// Output buffer float32, flat layout = reference return order:
//   [ discrete (131072) | quantized NCHW (8388608) | loss (1) ]
#define IDX_OFF  0
#define Q_OFF    N_ROWS
#define LOSS_OFF (N_ROWS + 32 * 64 * 4096)   // 8519680

#define RS      68     // xlds row stride (dwords): b128-aligned, 8 disjoint bank groups
#define TILE_R  64     // rows per block
#define NBLK    (N_ROWS / TILE_R)   // 2048

// numpy pairwise_sum (n=64) of squares, unit stride (validated bit-exact R5-R8)
#define NP_SUMSQ64(SRC, DST)                                                   \
    do {                                                                       \
        float r_[8];                                                           \
        _Pragma("unroll")                                                      \
        for (int j_ = 0; j_ < 8; ++j_) r_[j_] = __fmul_rn((SRC)[j_], (SRC)[j_]); \
        _Pragma("unroll")                                                      \
        for (int i_ = 8; i_ < 64; i_ += 8) {                                   \
            _Pragma("unroll")                                                  \
            for (int j_ = 0; j_ < 8; ++j_)                                     \
                r_[j_] = __fadd_rn(r_[j_], __fmul_rn((SRC)[i_ + j_], (SRC)[i_ + j_])); \
        }                                                                      \
        (DST) = __fadd_rn(__fadd_rn(__fadd_rn(r_[0], r_[1]), __fadd_rn(r_[2], r_[3])), \
                          __fadd_rn(__fadd_rn(r_[4], r_[5]), __fadd_rn(r_[6], r_[7]))); \
    } while (0)

// strided variant (for NCHW global x: element d at SRC[d*STRIDE])
#define NP_SUMSQ64_S(SRC, STRIDE, DST)                                         \
    do {                                                                       \
        float r_[8];                                                           \
        _Pragma("unroll")                                                      \
        for (int j_ = 0; j_ < 8; ++j_) {                                       \
            float v_ = (SRC)[j_ * (STRIDE)];                                   \
            r_[j_] = __fmul_rn(v_, v_);                                        \
        }                                                                      \
        _Pragma("unroll")                                                      \
        for (int i_ = 8; i_ < 64; i_ += 8) {                                   \
            _Pragma("unroll")                                                  \
            for (int j_ = 0; j_ < 8; ++j_) {                                   \
                float v_ = (SRC)[(i_ + j_) * (STRIDE)];                        \
                r_[j_] = __fadd_rn(r_[j_], __fmul_rn(v_, v_));                 \
            }                                                                  \
        }                                                                      \
        (DST) = __fadd_rn(__fadd_rn(__fadd_rn(r_[0], r_[1]), __fadd_rn(r_[2], r_[3])), \
                          __fadd_rn(__fadd_rn(r_[4], r_[5]), __fadd_rn(r_[6], r_[7]))); \
    } while (0)

// Fused kernel: 64 rows/block vs all 512 codes. Thread tile: 4 rows x 8 codes
// per chunk, 4 chunks (32 codes/thread across 16 tc lanes). w straight from
// global (L1/L2-hot, no LDS, no k-loop barriers); x in LDS (conflict-free).
__global__ __launch_bounds__(256, 2) void vq_gemm(const float* __restrict__ x_in,
                                                  const float* __restrict__ weight,
                                                  double* __restrict__ lslots,
                                                  float* __restrict__ out) {
    __shared__ float xlds[TILE_R * RS];    // 17408 B
    __shared__ float Asm[TILE_R];
    __shared__ float w2all[NUM_K];         // 2048 B
    __shared__ int   ilds[TILE_R];
    __shared__ float wsum[4];

    const int tid     = threadIdx.x;
    const int rowbase = blockIdx.x * TILE_R;
    const int b       = rowbase >> 12;
    const int hw0     = rowbase & 4095;    // 64-aligned, same b for whole tile
    const float* xb   = x_in + (size_t)b * CHW + hw0;

    // ---- stage x: 4 coalesced b32 global loads -> 1 conflict-free b128 LDS write ----
    #pragma unroll
    for (int u = 0; u < 4; ++u) {
        int f   = u * 256 + tid;          // 0..1023
        int row = f & 63, dq = f >> 6;    // dq 0..15
        float4 v = make_float4(xb[(dq * 4 + 0) * HW + row],
                               xb[(dq * 4 + 1) * HW + row],
                               xb[(dq * 4 + 2) * HW + row],
                               xb[(dq * 4 + 3) * HW + row]);
        *(float4*)&xlds[row * RS + dq * 4] = v;   // row-stride 68: 8 disjoint bank groups
    }
    // ---- w2all: numpy-pairwise ||w_k||^2, 2 codes/thread (validated) ----
    #pragma unroll
    for (int cc = 0; cc < 2; ++cc) {
        int c = cc * 256 + tid;
        const float* wk = weight + c * DIM;
        float s; NP_SUMSQ64(wk, s);
        w2all[c] = s;
    }
    // ---- Asm: per-row A = np.sum(x*x), wave 0 from global (strided-coalesced) ----
    if (tid < 64) {
        const float* src = xb + tid;      // row rowbase+tid, element d at src[d*HW]
        float s; NP_SUMSQ64_S(src, HW, s);
        Asm[tid] = s;
    }
    __syncthreads();

    const int tr = tid >> 4;   // 0..15 -> rows tr + 16*i, i=0..3
    const int tc = tid & 15;   // code class: codes tc + 16*jj, jj=0..31

    float Ai[4];
    #pragma unroll
    for (int i = 0; i < 4; ++i) Ai[i] = Asm[tr + 16 * i];

    float best[4];
    int   bidx[4];
    #pragma unroll
    for (int i = 0; i < 4; ++i) { best[i] = 3.4e38f; bidx[i] = 0; }

    // ---- barrier-free k-loop: 4 chunks x 8 codes ----
    for (int cc = 0; cc < 4; ++cc) {
        const float4* wp[8];
        int code0 = tc + 16 * (cc * 8);
        #pragma unroll
        for (int j = 0; j < 8; ++j)
            wp[j] = (const float4*)(weight + (size_t)(code0 + 16 * j) * DIM);

        float m[4][8];
        #pragma unroll
        for (int i = 0; i < 4; ++i)
            #pragma unroll
            for (int j = 0; j < 8; ++j) m[i][j] = 0.0f;

        #pragma unroll
        for (int q = 0; q < 16; ++q) {
            float4 xa[4];
            #pragma unroll
            for (int i = 0; i < 4; ++i)
                xa[i] = *(const float4*)&xlds[(tr + 16 * i) * RS + q * 4];
            #pragma unroll
            for (int j = 0; j < 8; ++j) {
                float4 wv = wp[j][q];     // global, L1/L2-hot
                #pragma unroll
                for (int i = 0; i < 4; ++i) {
                    // sequential d-chain per (row,code): sgemm semantics (bit-exact)
                    m[i][j] = __fmaf_rn(xa[i].x, wv.x, m[i][j]);
                    m[i][j] = __fmaf_rn(xa[i].y, wv.y, m[i][j]);
                    m[i][j] = __fmaf_rn(xa[i].z, wv.z, m[i][j]);
                    m[i][j] = __fmaf_rn(xa[i].w, wv.w, m[i][j]);
                }
            }
        }

        // dist + carried argmin (codes ascending over (cc,j): first-min kept)
        #pragma unroll
        for (int j = 0; j < 8; ++j) {
            int code = code0 + 16 * j;
            float w2 = w2all[code];
            #pragma unroll
            for (int i = 0; i < 4; ++i) {
                float dist = __fadd_rn(__fsub_rn(Ai[i], __fmul_rn(2.0f, m[i][j])), w2);
                if (dist < best[i]) { best[i] = dist; bidx[i] = code; }
            }
        }
    }

    // ---- cross-lane argmin per row: u64 key butterfly over 16 tc lanes ----
    #pragma unroll
    for (int i = 0; i < 4; ++i) {
        ull key = ((ull)__float_as_uint(best[i]) << 32) | (unsigned)bidx[i];
        #pragma unroll
        for (int mk = 1; mk <= 8; mk <<= 1) {
            ull o = __shfl_xor(key, mk);
            if (o < key) key = o;
        }
        if (tc == 0) {
            int row = tr + 16 * i;
            int idx = (int)(key & 0xffffffffu);
            ilds[row] = idx;
            out[IDX_OFF + rowbase + row] = (float)idx;
        }
    }
    __syncthreads();   // ilds visible

    // ---- quantize epilogue + loss: x from xlds (conflict-free b128), w from L2 ----
    float lsum = 0.0f;
    float* oqb = out + Q_OFF + (size_t)b * CHW + hw0;
    #pragma unroll
    for (int u = 0; u < 4; ++u) {
        int f   = u * 256 + tid;
        int row = f & 63, dq = f >> 6;
        float4 xv = *(const float4*)&xlds[row * RS + dq * 4];
        const float4* wq = (const float4*)(weight + (size_t)ilds[row] * DIM);
        float4 wv = wq[dq];
        float dx = __fsub_rn(wv.x, xv.x), dy = __fsub_rn(wv.y, xv.y);
        float dz = __fsub_rn(wv.z, xv.z), dw = __fsub_rn(wv.w, xv.w);
        oqb[(dq * 4 + 0) * HW + row] = __fadd_rn(xv.x, dx);   // straight-through
        oqb[(dq * 4 + 1) * HW + row] = __fadd_rn(xv.y, dy);
        oqb[(dq * 4 + 2) * HW + row] = __fadd_rn(xv.z, dz);
        oqb[(dq * 4 + 3) * HW + row] = __fadd_rn(xv.w, dw);
        lsum = fmaf(dx, dx, lsum); lsum = fmaf(dy, dy, lsum); // loss tol 2%
        lsum = fmaf(dz, dz, lsum); lsum = fmaf(dw, dw, lsum);
    }

    #pragma unroll
    for (int off = 32; off > 0; off >>= 1) lsum += __shfl_down(lsum, off);
    if ((tid & 63) == 0) wsum[tid >> 6] = lsum;
    __syncthreads();
    if (tid == 0)
        lslots[blockIdx.x] = (double)((wsum[0] + wsum[1]) + (wsum[2] + wsum[3]));
}

__global__ void vq_finalize3(const double* __restrict__ lslots,
                             float* __restrict__ out) {
    double s = 0.0;
    for (int i = threadIdx.x; i < NBLK; i += 64) s += lslots[i];
    #pragma unroll
    for (int off = 32; off > 0; off >>= 1) s += __shfl_down(s, off);
    if (threadIdx.x == 0) {
        double m = s / 8388608.0;
        out[LOSS_OFF] = (float)(m + 0.25 * m);   // q_latent + 0.25 * e_latent
    }
}

// ---------------- fallback (R5-validated fused path, used only if ws tiny) ----
__global__ void vq_zero(double* __restrict__ loss_acc) {
    if (threadIdx.x == 0) *loss_acc = 0.0;
}

__global__ __launch_bounds__(256) void vq_fused(const float* __restrict__ x_in,
                                                const float* __restrict__ weight,
                                                double* __restrict__ loss_acc,
                                                float* __restrict__ out) {
    __shared__ float w2s[NUM_K];
    for (int k = threadIdx.x; k < NUM_K; k += 256) {
        const float* wk = weight + k * DIM;
        float s; NP_SUMSQ64(wk, s);
        w2s[k] = s;
    }
    __syncthreads();

    const int n  = blockIdx.x * 256 + threadIdx.x;
    const int b  = n >> 12;
    const int hw = n & 4095;
    const float* xp = x_in + b * CHW + hw;
    float x[DIM];
    #pragma unroll
    for (int d = 0; d < DIM; ++d) x[d] = xp[d * HW];

    float A; NP_SUMSQ64(x, A);

    float best = 3.4e38f;
    int   bi   = 0;
    for (int k = 0; k < NUM_K; k += 4) {
        const float* w0 = weight + k * DIM;
        float m0 = 0.f, m1 = 0.f, m2 = 0.f, m3 = 0.f;
        #pragma unroll
        for (int d = 0; d < DIM; ++d) {
            float xd = x[d];
            m0 = __fmaf_rn(xd, w0[d],           m0);
            m1 = __fmaf_rn(xd, w0[DIM + d],     m1);
            m2 = __fmaf_rn(xd, w0[2 * DIM + d], m2);
            m3 = __fmaf_rn(xd, w0[3 * DIM + d], m3);
        }
        float d0 = __fadd_rn(__fsub_rn(A, __fmul_rn(2.0f, m0)), w2s[k]);
        float d1 = __fadd_rn(__fsub_rn(A, __fmul_rn(2.0f, m1)), w2s[k + 1]);
        float d2 = __fadd_rn(__fsub_rn(A, __fmul_rn(2.0f, m2)), w2s[k + 2]);
        float d3 = __fadd_rn(__fsub_rn(A, __fmul_rn(2.0f, m3)), w2s[k + 3]);
        if (d0 < best) { best = d0; bi = k; }
        if (d1 < best) { best = d1; bi = k + 1; }
        if (d2 < best) { best = d2; bi = k + 2; }
        if (d3 < best) { best = d3; bi = k + 3; }
    }
    const int idx = bi;

    out[IDX_OFF + n] = (float)idx;
    const float* qrow = weight + idx * DIM;
    float* oq = out + Q_OFF + b * CHW + hw;
    float lsum = 0.0f;
    #pragma unroll
    for (int d = 0; d < DIM; ++d) {
        float xd   = xp[d * HW];
        float diff = __fsub_rn(qrow[d], xd);
        oq[d * HW] = __fadd_rn(xd, diff);
        lsum = fmaf(diff, diff, lsum);
    }
    #pragma unroll
    for (int off = 32; off > 0; off >>= 1) lsum += __shfl_down(lsum, off);
    __shared__ float wsum[4];
    if ((threadIdx.x & 63) == 0) wsum[threadIdx.x >> 6] = lsum;
    __syncthreads();
    if (threadIdx.x == 0)
        atomicAdd(loss_acc, (double)((wsum[0] + wsum[1]) + (wsum[2] + wsum[3])));
}

__global__ void vq_finalize(const double* __restrict__ loss_acc,
                            float* __restrict__ out) {
    double m = *loss_acc / 8388608.0;
    out[LOSS_OFF] = (float)(m + 0.25 * m);
}

extern "C" void kernel_launch(void* const* d_in, const int* in_sizes, int n_in,
                              void* d_out, int out_size, void* d_ws, size_t ws_size,
                              hipStream_t stream) {
    const float* x = (const float*)d_in[0];    // inputs  [32,64,64,64] NCHW fp32
    const float* w = (const float*)d_in[1];    // weight  [512,64] fp32
    float* out = (float*)d_out;

    if (ws_size >= NBLK * sizeof(double)) {
        double* lslots = (double*)d_ws;        // 16 KB: per-block loss partials
        vq_gemm<<<NBLK, 256, 0, stream>>>(x, w, lslots, out);
        vq_finalize3<<<1, 64, 0, stream>>>(lslots, out);
    } else {
        double* loss_acc = (double*)d_ws;      // 8 bytes
        vq_zero<<<1, 64, 0, stream>>>(loss_acc);
        vq_fused<<<512, 256, 0, stream>>>(x, w, loss_acc, out);
        vq_finalize<<<1, 1, 0, stream>>>(loss_acc, out);
    }
}

// Round 10
// 240.858 us; speedup vs baseline: 3.1033x; 3.1033x over previous
//
#include <hip/hip_runtime.h>

typedef unsigned long long ull;

#define NUM_K   512
#define DIM     64
#define N_ROWS  (32 * 64 * 64)     // 131072 rows
#define HW      4096               // 64*64
#define CHW     (64 * 4096)        // per-batch stride (C*H*W)

// Output buffer float32, flat layout = reference return order:
//   [ discrete (131072) | quantized NCHW (8388608) | loss (1) ]
#define IDX_OFF  0
#define Q_OFF    N_ROWS
#define LOSS_OFF (N_ROWS + 32 * 64 * 4096)   // 8519680

#define RS      68     // xlds row stride (dwords): b128-aligned, conflict-free (R8/R9: 0 conflicts)
#define TILE_R  64     // rows per block
#define NBLK    (N_ROWS / TILE_R)   // 2048

// numpy pairwise_sum (n=64) of squares, unit stride (validated bit-exact R5-R9)
#define NP_SUMSQ64(SRC, DST)                                                   \
    do {                                                                       \
        float r_[8];                                                           \
        _Pragma("unroll")                                                      \
        for (int j_ = 0; j_ < 8; ++j_) r_[j_] = __fmul_rn((SRC)[j_], (SRC)[j_]); \
        _Pragma("unroll")                                                      \
        for (int i_ = 8; i_ < 64; i_ += 8) {                                   \
            _Pragma("unroll")                                                  \
            for (int j_ = 0; j_ < 8; ++j_)                                     \
                r_[j_] = __fadd_rn(r_[j_], __fmul_rn((SRC)[i_ + j_], (SRC)[i_ + j_])); \
        }                                                                      \
        (DST) = __fadd_rn(__fadd_rn(__fadd_rn(r_[0], r_[1]), __fadd_rn(r_[2], r_[3])), \
                          __fadd_rn(__fadd_rn(r_[4], r_[5]), __fadd_rn(r_[6], r_[7]))); \
    } while (0)

// strided variant (for NCHW global x) — validated R9
#define NP_SUMSQ64_S(SRC, STRIDE, DST)                                         \
    do {                                                                       \
        float r_[8];                                                           \
        _Pragma("unroll")                                                      \
        for (int j_ = 0; j_ < 8; ++j_) {                                       \
            float v_ = (SRC)[j_ * (STRIDE)];                                   \
            r_[j_] = __fmul_rn(v_, v_);                                        \
        }                                                                      \
        _Pragma("unroll")                                                      \
        for (int i_ = 8; i_ < 64; i_ += 8) {                                   \
            _Pragma("unroll")                                                  \
            for (int j_ = 0; j_ < 8; ++j_) {                                   \
                float v_ = (SRC)[(i_ + j_) * (STRIDE)];                        \
                r_[j_] = __fadd_rn(r_[j_], __fmul_rn(v_, v_));                 \
            }                                                                  \
        }                                                                      \
        (DST) = __fadd_rn(__fadd_rn(__fadd_rn(r_[0], r_[1]), __fadd_rn(r_[2], r_[3])), \
                          __fadd_rn(__fadd_rn(r_[4], r_[5]), __fadd_rn(r_[6], r_[7]))); \
    } while (0)

// Fused kernel: 64 rows/block, lane = row. Each of the 4 waves owns 128
// wave-uniform codes -> weights via the SCALAR pipe (s_load + SGPR-operand
// v_fmac). x via one conflict-free ds_read_b128 per d-quad, reused across
// 16 codes: 64 FMA per DS instruction.
__global__ __launch_bounds__(256, 4) void vq_scalar(const float* __restrict__ x_in,
                                                    const float* __restrict__ weight,
                                                    double* __restrict__ lslots,
                                                    float* __restrict__ out) {
    __shared__ float xlds[TILE_R * RS];    // 17408 B
    __shared__ float Asm[TILE_R];
    __shared__ float w2all[NUM_K];         // 2048 B
    __shared__ ull   keys4[4][TILE_R];     // 2048 B
    __shared__ int   ilds[TILE_R];
    __shared__ float wsum[4];

    const int tid     = threadIdx.x;
    const int rowbase = blockIdx.x * TILE_R;
    const int b       = rowbase >> 12;
    const int hw0     = rowbase & 4095;    // 64-aligned, same b for whole tile
    const float* xb   = x_in + (size_t)b * CHW + hw0;

    // ---- stage x: 4 coalesced b32 global loads -> conflict-free b128 LDS write (R9) ----
    #pragma unroll
    for (int u = 0; u < 4; ++u) {
        int f   = u * 256 + tid;          // 0..1023
        int row = f & 63, dq = f >> 6;    // dq 0..15
        float4 v = make_float4(xb[(dq * 4 + 0) * HW + row],
                               xb[(dq * 4 + 1) * HW + row],
                               xb[(dq * 4 + 2) * HW + row],
                               xb[(dq * 4 + 3) * HW + row]);
        *(float4*)&xlds[row * RS + dq * 4] = v;
    }
    // ---- w2all: numpy-pairwise ||w_k||^2 (validated) ----
    #pragma unroll
    for (int cc = 0; cc < 2; ++cc) {
        int c = cc * 256 + tid;
        const float* wk = weight + c * DIM;
        float s; NP_SUMSQ64(wk, s);
        w2all[c] = s;
    }
    // ---- Asm: per-row A = np.sum(x*x) from global, strided-coalesced (R9) ----
    if (tid < 64) {
        const float* src = xb + tid;
        float s; NP_SUMSQ64_S(src, HW, s);
        Asm[tid] = s;
    }
    __syncthreads();

    const int lane = tid & 63;
    const int wid  = tid >> 6;
    const float A  = Asm[lane];
    const float4* xrow = (const float4*)&xlds[lane * RS];

    float best = 3.4e38f;
    int   bidx = 0;
    const int wbase = wid * 128;           // this wave's 128 codes (ascending)

    for (int g = 0; g < 8; ++g) {
        // force wave-uniform scalar base -> s_load path for weights
        const int c0 = __builtin_amdgcn_readfirstlane(wbase + g * 16);
        const float* wgp = weight + (size_t)c0 * DIM;

        float m[16];
        #pragma unroll
        for (int j = 0; j < 16; ++j) m[j] = 0.0f;

        #pragma unroll
        for (int q = 0; q < 16; ++q) {
            float4 xa = xrow[q];           // 1 ds_read_b128, reused for 16 codes
            #pragma unroll
            for (int j = 0; j < 16; ++j) {
                float4 wv = *(const float4*)(wgp + j * DIM + q * 4);  // s_load_dwordx4
                // sequential d-chain per (row,code): sgemm semantics (bit-exact R5-R9)
                m[j] = __fmaf_rn(xa.x, wv.x, m[j]);
                m[j] = __fmaf_rn(xa.y, wv.y, m[j]);
                m[j] = __fmaf_rn(xa.z, wv.z, m[j]);
                m[j] = __fmaf_rn(xa.w, wv.w, m[j]);
            }
        }
        // dist + carried argmin; codes ascending over (g,j) -> first-min kept
        #pragma unroll
        for (int j = 0; j < 16; ++j) {
            int code = c0 + j;
            float dist = __fadd_rn(__fsub_rn(A, __fmul_rn(2.0f, m[j])), w2all[code]);
            if (dist < best) { best = dist; bidx = code; }
        }
    }

    // ---- cross-wave argmin per row (race-free LDS table, u64 keys) ----
    keys4[wid][lane] = ((ull)__float_as_uint(best) << 32) | (unsigned)bidx;
    __syncthreads();
    if (tid < 64) {
        ull k = keys4[0][tid];
        #pragma unroll
        for (int w = 1; w < 4; ++w) { ull t = keys4[w][tid]; if (t < k) k = t; }
        int idx = (int)(k & 0xffffffffu);
        ilds[tid] = idx;
        out[IDX_OFF + rowbase + tid] = (float)idx;
    }
    __syncthreads();

    // ---- quantize epilogue + loss: x from xlds (conflict-free), w from L2 (R9) ----
    float lsum = 0.0f;
    float* oqb = out + Q_OFF + (size_t)b * CHW + hw0;
    #pragma unroll
    for (int u = 0; u < 4; ++u) {
        int f   = u * 256 + tid;
        int row = f & 63, dq = f >> 6;
        float4 xv = *(const float4*)&xlds[row * RS + dq * 4];
        const float4* wq = (const float4*)(weight + (size_t)ilds[row] * DIM);
        float4 wv = wq[dq];
        float dx = __fsub_rn(wv.x, xv.x), dy = __fsub_rn(wv.y, xv.y);
        float dz = __fsub_rn(wv.z, xv.z), dw = __fsub_rn(wv.w, xv.w);
        oqb[(dq * 4 + 0) * HW + row] = __fadd_rn(xv.x, dx);   // straight-through
        oqb[(dq * 4 + 1) * HW + row] = __fadd_rn(xv.y, dy);
        oqb[(dq * 4 + 2) * HW + row] = __fadd_rn(xv.z, dz);
        oqb[(dq * 4 + 3) * HW + row] = __fadd_rn(xv.w, dw);
        lsum = fmaf(dx, dx, lsum); lsum = fmaf(dy, dy, lsum);  // loss tol 2%
        lsum = fmaf(dz, dz, lsum); lsum = fmaf(dw, dw, lsum);
    }

    #pragma unroll
    for (int off = 32; off > 0; off >>= 1) lsum += __shfl_down(lsum, off);
    if ((tid & 63) == 0) wsum[tid >> 6] = lsum;
    __syncthreads();
    if (tid == 0)
        lslots[blockIdx.x] = (double)((wsum[0] + wsum[1]) + (wsum[2] + wsum[3]));
}

__global__ void vq_finalize3(const double* __restrict__ lslots,
                             float* __restrict__ out) {
    double s = 0.0;
    for (int i = threadIdx.x; i < NBLK; i += 64) s += lslots[i];
    #pragma unroll
    for (int off = 32; off > 0; off >>= 1) s += __shfl_down(s, off);
    if (threadIdx.x == 0) {
        double m = s / 8388608.0;
        out[LOSS_OFF] = (float)(m + 0.25 * m);   // q_latent + 0.25 * e_latent
    }
}

// ---------------- fallback (R5-validated fused path, used only if ws tiny) ----
__global__ void vq_zero(double* __restrict__ loss_acc) {
    if (threadIdx.x == 0) *loss_acc = 0.0;
}

__global__ __launch_bounds__(256) void vq_fused(const float* __restrict__ x_in,
                                                const float* __restrict__ weight,
                                                double* __restrict__ loss_acc,
                                                float* __restrict__ out) {
    __shared__ float w2s[NUM_K];
    for (int k = threadIdx.x; k < NUM_K; k += 256) {
        const float* wk = weight + k * DIM;
        float s; NP_SUMSQ64(wk, s);
        w2s[k] = s;
    }
    __syncthreads();

    const int n  = blockIdx.x * 256 + threadIdx.x;
    const int b  = n >> 12;
    const int hw = n & 4095;
    const float* xp = x_in + b * CHW + hw;
    float x[DIM];
    #pragma unroll
    for (int d = 0; d < DIM; ++d) x[d] = xp[d * HW];

    float A; NP_SUMSQ64(x, A);

    float best = 3.4e38f;
    int   bi   = 0;
    for (int k = 0; k < NUM_K; k += 4) {
        const float* w0 = weight + k * DIM;
        float m0 = 0.f, m1 = 0.f, m2 = 0.f, m3 = 0.f;
        #pragma unroll
        for (int d = 0; d < DIM; ++d) {
            float xd = x[d];
            m0 = __fmaf_rn(xd, w0[d],           m0);
            m1 = __fmaf_rn(xd, w0[DIM + d],     m1);
            m2 = __fmaf_rn(xd, w0[2 * DIM + d], m2);
            m3 = __fmaf_rn(xd, w0[3 * DIM + d], m3);
        }
        float d0 = __fadd_rn(__fsub_rn(A, __fmul_rn(2.0f, m0)), w2s[k]);
        float d1 = __fadd_rn(__fsub_rn(A, __fmul_rn(2.0f, m1)), w2s[k + 1]);
        float d2 = __fadd_rn(__fsub_rn(A, __fmul_rn(2.0f, m2)), w2s[k + 2]);
        float d3 = __fadd_rn(__fsub_rn(A, __fmul_rn(2.0f, m3)), w2s[k + 3]);
        if (d0 < best) { best = d0; bi = k; }
        if (d1 < best) { best = d1; bi = k + 1; }
        if (d2 < best) { best = d2; bi = k + 2; }
        if (d3 < best) { best = d3; bi = k + 3; }
    }
    const int idx = bi;

    out[IDX_OFF + n] = (float)idx;
    const float* qrow = weight + idx * DIM;
    float* oq = out + Q_OFF + b * CHW + hw;
    float lsum = 0.0f;
    #pragma unroll
    for (int d = 0; d < DIM; ++d) {
        float xd   = xp[d * HW];
        float diff = __fsub_rn(qrow[d], xd);
        oq[d * HW] = __fadd_rn(xd, diff);
        lsum = fmaf(diff, diff, lsum);
    }
    #pragma unroll
    for (int off = 32; off > 0; off >>= 1) lsum += __shfl_down(lsum, off);
    __shared__ float wsum[4];
    if ((threadIdx.x & 63) == 0) wsum[threadIdx.x >> 6] = lsum;
    __syncthreads();
    if (threadIdx.x == 0)
        atomicAdd(loss_acc, (double)((wsum[0] + wsum[1]) + (wsum[2] + wsum[3])));
}

__global__ void vq_finalize(const double* __restrict__ loss_acc,
                            float* __restrict__ out) {
    double m = *loss_acc / 8388608.0;
    out[LOSS_OFF] = (float)(m + 0.25 * m);
}

extern "C" void kernel_launch(void* const* d_in, const int* in_sizes, int n_in,
                              void* d_out, int out_size, void* d_ws, size_t ws_size,
                              hipStream_t stream) {
    const float* x = (const float*)d_in[0];    // inputs  [32,64,64,64] NCHW fp32
    const float* w = (const float*)d_in[1];    // weight  [512,64] fp32
    float* out = (float*)d_out;

    if (ws_size >= NBLK * sizeof(double)) {
        double* lslots = (double*)d_ws;        // 16 KB: per-block loss partials
        vq_scalar<<<NBLK, 256, 0, stream>>>(x, w, lslots, out);
        vq_finalize3<<<1, 64, 0, stream>>>(lslots, out);
    } else {
        double* loss_acc = (double*)d_ws;      // 8 bytes
        vq_zero<<<1, 64, 0, stream>>>(loss_acc);
        vq_fused<<<512, 256, 0, stream>>>(x, w, loss_acc, out);
        vq_finalize<<<1, 1, 0, stream>>>(loss_acc, out);
    }
}